// Round 1
// baseline (623.101 us; speedup 1.0000x reference)
//
#include <hip/hip_runtime.h>
#include <hip/hip_bf16.h>
#include <math.h>

#define Bz 131072
#define Dd 256
#define Hh 256
#define Ee 4

typedef __attribute__((ext_vector_type(8))) short short8;
typedef __attribute__((ext_vector_type(4))) float f32x4;
typedef __attribute__((ext_vector_type(4))) unsigned short u16x4;

__device__ __forceinline__ unsigned short f2bf(float f) {
    union { float f; unsigned int u; } v; v.f = f;
    unsigned int r = v.u + 0x7FFFu + ((v.u >> 16) & 1u);   // RNE
    return (unsigned short)(r >> 16);
}

#define MFMA16(a, b, c) __builtin_amdgcn_mfma_f32_16x16x32_bf16(a, b, c, 0, 0, 0)

// ---------- prep: W1 (E,D,H) -> W1t bf16 (E,H,D); W2 (E,H,D) -> W2t bf16 (E,D,H); zero counts
__global__ __launch_bounds__(256) void prep_kernel(const float* __restrict__ W1,
                                                   const float* __restrict__ W2,
                                                   unsigned short* __restrict__ W1t,
                                                   unsigned short* __restrict__ W2t,
                                                   unsigned int* __restrict__ counts) {
    int idx = blockIdx.x * 256 + threadIdx.x;          // 0 .. 262143
    if (idx < 4) counts[idx] = 0u;
    int e = idx >> 16, a = (idx >> 8) & 255, b = idx & 255;
    int src = (e << 16) + (b << 8) + a;                // out[e][a][b] = in[e][b][a]
    W1t[idx] = f2bf(W1[src]);
    W2t[idx] = f2bf(W2[src]);
}

// ---------- gating: f64 distances -> top-2 -> softmax weights (dense B x 4) + counts
__global__ __launch_bounds__(256) void gate_kernel(const float* __restrict__ z,
                                                   const int* __restrict__ ridx_p,
                                                   const float* __restrict__ centroids,
                                                   const float* __restrict__ tau_raw,
                                                   float* __restrict__ wdense,
                                                   unsigned int* __restrict__ counts) {
    __shared__ unsigned int scnt[4];
    int tid = threadIdx.x;
    if (tid < 4) scnt[tid] = 0u;
    __syncthreads();
    int lane = tid & 63;
    int gwave = (blockIdx.x * 256 + tid) >> 6;         // 0 .. 8191, 16 rows each
    int ridx = ridx_p[0];
    double tau = log1p(exp((double)tau_raw[ridx])) + 1e-6;
    const float* cb = centroids + (size_t)ridx * (Ee * Dd);
    float c[4][4];
#pragma unroll
    for (int e = 0; e < 4; ++e) {
        f32x4 cv = *(const f32x4*)(cb + e * 256 + lane * 4);
#pragma unroll
        for (int j = 0; j < 4; ++j) c[e][j] = cv[j];
    }
    for (int rr = 0; rr < 16; ++rr) {
        int row = gwave * 16 + rr;
        f32x4 zv = *(const f32x4*)(z + (size_t)row * 256 + lane * 4);
        double d2[4] = {0.0, 0.0, 0.0, 0.0};
#pragma unroll
        for (int e = 0; e < 4; ++e)
#pragma unroll
            for (int j = 0; j < 4; ++j) {
                double df = (double)zv[j] - (double)c[e][j];
                d2[e] += df * df;
            }
#pragma unroll
        for (int m = 32; m >= 1; m >>= 1)
#pragma unroll
            for (int e = 0; e < 4; ++e) d2[e] += __shfl_xor(d2[e], m, 64);
        if (lane == 0) {
            int e1 = 0;
#pragma unroll
            for (int e = 1; e < 4; ++e) if (d2[e] < d2[e1]) e1 = e;
            int e2 = (e1 == 0) ? 1 : 0;
#pragma unroll
            for (int e = 0; e < 4; ++e)
                if (e != e1 && e != e2 && d2[e] < d2[e2]) e2 = e;
            double s1 = exp(-sqrt(d2[e1]) / tau);
            double s2 = exp(-sqrt(d2[e2]) / tau);
            double w1 = 1.0 / (1.0 + exp(s2 - s1));    // softmax over [s1,s2]
            f32x4 wv;
#pragma unroll
            for (int j = 0; j < 4; ++j)
                wv[j] = (j == e1) ? (float)w1 : ((j == e2) ? (float)(1.0 - w1) : 0.0f);
            *(f32x4*)(wdense + (size_t)row * 4) = wv;
            atomicAdd(&scnt[e1], 1u);
            atomicAdd(&scnt[e2], 1u);
        }
    }
    __syncthreads();
    if (tid < 4) atomicAdd(&counts[tid], scnt[tid]);
}

// ---------- fused FFN + combine + residual + LayerNorm
// 64-row tile per block; 4 waves, wave w owns output cols [w*64, w*64+64)
__global__ __launch_bounds__(256, 2) void ffn_kernel(const float* __restrict__ z,
    const unsigned short* __restrict__ W1t, const unsigned short* __restrict__ W2t,
    const float* __restrict__ b1, const float* __restrict__ b2,
    const float* __restrict__ wdense, const float* __restrict__ ln_g,
    const float* __restrict__ ln_b, float* __restrict__ y) {
    __shared__ char lds[65536];      // [0,32K): Z bf16 swz | [32K,64K): H1 bf16 swz | later: x f32
    __shared__ float wd_s[256];
    int tid = threadIdx.x;
    int lane = tid & 63;
    int wv = tid >> 6;
    int r0 = blockIdx.x * 64;

    // stage Z -> bf16, XOR-swizzled rows
#pragma unroll
    for (int it = 0; it < 16; ++it) {
        int idx = it * 256 + tid;                      // 4096 float4 chunks
        int r = idx >> 6;
        int cq = (idx & 63) << 2;
        f32x4 v = *(const f32x4*)(z + (size_t)(r0 + r) * 256 + cq);
        u16x4 hv;
        hv[0] = f2bf(v[0]); hv[1] = f2bf(v[1]); hv[2] = f2bf(v[2]); hv[3] = f2bf(v[3]);
        *(u16x4*)(&lds[(r * 512 + cq * 2) ^ ((r & 7) << 4)]) = hv;
    }
    wd_s[tid] = wdense[(size_t)r0 * 4 + tid];
    __syncthreads();

    int ln15 = lane & 15;
    int lhi = lane >> 4;
    int nbase = wv * 64;

    f32x4 accx[4][4];
#pragma unroll
    for (int i = 0; i < 4; ++i)
#pragma unroll
        for (int j = 0; j < 4; ++j) accx[i][j] = (f32x4)0.0f;

    for (int e = 0; e < 4; ++e) {
        const unsigned short* w1p = W1t + (e << 16);
        const unsigned short* w2p = W2t + (e << 16);

        // ---- GEMM1: H1pre = Z @ W1[e]
        f32x4 acc1[4][4];
#pragma unroll
        for (int i = 0; i < 4; ++i)
#pragma unroll
            for (int j = 0; j < 4; ++j) acc1[i][j] = (f32x4)0.0f;
#pragma unroll
        for (int ks = 0; ks < 8; ++ks) {
            int krow = ks * 32 + lhi * 8;
            short8 a[4], b[4];
#pragma unroll
            for (int fr = 0; fr < 4; ++fr) {
                int r = fr * 16 + ln15;
                a[fr] = *(const short8*)(&lds[(r * 512 + krow * 2) ^ ((r & 7) << 4)]);
            }
#pragma unroll
            for (int fc = 0; fc < 4; ++fc) {
                int hcol = nbase + fc * 16 + ln15;
                b[fc] = *(const short8*)(w1p + hcol * 256 + krow);
            }
#pragma unroll
            for (int fr = 0; fr < 4; ++fr)
#pragma unroll
                for (int fc = 0; fc < 4; ++fc)
                    acc1[fr][fc] = MFMA16(a[fr], b[fc], acc1[fr][fc]);
        }
        // ---- epilogue1: +b1, exact gelu, -> H1 bf16 (swizzled)
#pragma unroll
        for (int fc = 0; fc < 4; ++fc) {
            int hcol = nbase + fc * 16 + ln15;
            float bb = b1[e * 256 + hcol];
#pragma unroll
            for (int fr = 0; fr < 4; ++fr)
#pragma unroll
                for (int i = 0; i < 4; ++i) {
                    float x = acc1[fr][fc][i] + bb;
                    float g = 0.5f * x * (1.0f + erff(x * 0.70710678118f));
                    int row = fr * 16 + lhi * 4 + i;
                    *(unsigned short*)(&lds[32768 + ((row * 512 + hcol * 2) ^ ((row & 7) << 4))]) = f2bf(g);
                }
        }
        __syncthreads();

        // ---- GEMM2: out = gelu(H1) @ W2[e]
        f32x4 acc2[4][4];
#pragma unroll
        for (int i = 0; i < 4; ++i)
#pragma unroll
            for (int j = 0; j < 4; ++j) acc2[i][j] = (f32x4)0.0f;
#pragma unroll
        for (int ks = 0; ks < 8; ++ks) {
            int krow = ks * 32 + lhi * 8;
            short8 a[4], b[4];
#pragma unroll
            for (int fr = 0; fr < 4; ++fr) {
                int r = fr * 16 + ln15;
                a[fr] = *(const short8*)(&lds[32768 + ((r * 512 + krow * 2) ^ ((r & 7) << 4))]);
            }
#pragma unroll
            for (int fc = 0; fc < 4; ++fc) {
                int dcol = nbase + fc * 16 + ln15;
                b[fc] = *(const short8*)(w2p + dcol * 256 + krow);
            }
#pragma unroll
            for (int fr = 0; fr < 4; ++fr)
#pragma unroll
                for (int fc = 0; fc < 4; ++fc)
                    acc2[fr][fc] = MFMA16(a[fr], b[fc], acc2[fr][fc]);
        }
        // ---- fold: accx += w_e * (out + b2[e])
#pragma unroll
        for (int fc = 0; fc < 4; ++fc) {
            int dcol = nbase + fc * 16 + ln15;
            float b2v = b2[e * 256 + dcol];
#pragma unroll
            for (int fr = 0; fr < 4; ++fr)
#pragma unroll
                for (int i = 0; i < 4; ++i) {
                    int row = fr * 16 + lhi * 4 + i;
                    float w = wd_s[row * 4 + e];
                    accx[fr][fc][i] += w * (acc2[fr][fc][i] + b2v);
                }
        }
        __syncthreads();   // all waves done reading H1 before next expert rewrites it
    }

    // ---- x = moe_out staged to LDS f32 (overwrites Z/H1)
#pragma unroll
    for (int fc = 0; fc < 4; ++fc)
#pragma unroll
        for (int fr = 0; fr < 4; ++fr)
#pragma unroll
            for (int i = 0; i < 4; ++i) {
                int row = fr * 16 + lhi * 4 + i;
                int col = nbase + fc * 16 + ln15;
                *(float*)(&lds[row * 1024 + col * 4]) = accx[fr][fc][i];
            }
    __syncthreads();

    // ---- residual + LayerNorm; wave handles rows [wv*16, wv*16+16)
    f32x4 gam = *(const f32x4*)(ln_g + lane * 4);
    f32x4 bet = *(const f32x4*)(ln_b + lane * 4);
    for (int rr = 0; rr < 16; ++rr) {
        int row = wv * 16 + rr;
        f32x4 xv = *(const f32x4*)(&lds[row * 1024 + lane * 16]);
        f32x4 zv = *(const f32x4*)(z + (size_t)(r0 + row) * 256 + lane * 4);
#pragma unroll
        for (int j = 0; j < 4; ++j) xv[j] += zv[j];
        float s = xv[0] + xv[1] + xv[2] + xv[3];
        float s2 = xv[0]*xv[0] + xv[1]*xv[1] + xv[2]*xv[2] + xv[3]*xv[3];
#pragma unroll
        for (int m = 32; m >= 1; m >>= 1) {
            s  += __shfl_xor(s, m, 64);
            s2 += __shfl_xor(s2, m, 64);
        }
        float mu = s * (1.0f / 256.0f);
        float var = s2 * (1.0f / 256.0f) - mu * mu;
        float rs = rsqrtf(var + 1e-5f);
        f32x4 yv;
#pragma unroll
        for (int j = 0; j < 4; ++j) yv[j] = gam[j] * ((xv[j] - mu) * rs) + bet[j];
        *(f32x4*)(y + (size_t)(r0 + row) * 256 + lane * 4) = yv;
    }
}

// ---------- finalize: expert utilization (exact: /2^18)
__global__ void final_kernel(const unsigned int* __restrict__ counts, float* __restrict__ out) {
    int t = threadIdx.x;
    if (t < 4) out[(size_t)Bz * Dd + t] = (float)counts[t] * (1.0f / 262144.0f);
}

extern "C" void kernel_launch(void* const* d_in, const int* in_sizes, int n_in,
                              void* d_out, int out_size, void* d_ws, size_t ws_size,
                              hipStream_t stream) {
    const float* z         = (const float*)d_in[0];
    const int*   ridx      = (const int*)d_in[1];
    const float* centroids = (const float*)d_in[2];
    const float* tau_raw   = (const float*)d_in[3];
    const float* W1        = (const float*)d_in[4];
    const float* b1        = (const float*)d_in[5];
    const float* W2        = (const float*)d_in[6];
    const float* b2        = (const float*)d_in[7];
    const float* lng       = (const float*)d_in[8];
    const float* lnb       = (const float*)d_in[9];
    float* out = (float*)d_out;

    unsigned short* W1t   = (unsigned short*)d_ws;                          // 512 KB
    unsigned short* W2t   = (unsigned short*)((char*)d_ws + 524288);        // 512 KB
    float*          wdense = (float*)((char*)d_ws + 1048576);               // 2 MB
    unsigned int*   counts = (unsigned int*)((char*)d_ws + 3145728);        // 16 B

    hipLaunchKernelGGL(prep_kernel, dim3(1024), dim3(256), 0, stream, W1, W2, W1t, W2t, counts);
    hipLaunchKernelGGL(gate_kernel, dim3(2048), dim3(256), 0, stream, z, ridx, centroids, tau_raw, wdense, counts);
    hipLaunchKernelGGL(ffn_kernel, dim3(2048), dim3(256), 0, stream, z, W1t, W2t, b1, b2, wdense, lng, lnb, out);
    hipLaunchKernelGGL(final_kernel, dim3(1), dim3(64), 0, stream, counts, out);
}